// Round 1
// baseline (713.262 us; speedup 1.0000x reference)
//
#include <hip/hip_runtime.h>

#define N_NODES 50000
#define N_EDGES 800000
#define F 96
#define F4 24          // F/4
#define NG 100
#define NC 8
#define TROWS 64       // gemm row tile
#define GB 192         // gemm block threads: 8 row-groups x 24 float4-cols
#define LDST 25        // LDS row stride in float4 (=100 floats, pad kills bank conflicts)

// ---------- CSR build ----------
__global__ void k_count(const int* __restrict__ ei, int* __restrict__ cnt) {
    int e = blockIdx.x * blockDim.x + threadIdx.x;
    if (e < N_EDGES) atomicAdd(&cnt[ei[N_EDGES + e]], 1);  // dst row
}

__global__ __launch_bounds__(1024) void k_scan(const int* __restrict__ cnt,
                                               int* __restrict__ rowptr,
                                               int* __restrict__ cursor) {
    __shared__ int sums[1024];
    int tid = threadIdx.x;
    const int CH = (N_NODES + 1023) / 1024;  // 49
    int start = tid * CH;
    int s = 0;
    for (int i = 0; i < CH; i++) {
        int idx = start + i;
        if (idx < N_NODES) s += cnt[idx];
    }
    sums[tid] = s;
    __syncthreads();
    for (int off = 1; off < 1024; off <<= 1) {
        int v = 0;
        if (tid >= off) v = sums[tid - off];
        __syncthreads();
        if (tid >= off) sums[tid] += v;
        __syncthreads();
    }
    int excl = (tid == 0) ? 0 : sums[tid - 1];
    for (int i = 0; i < CH; i++) {
        int idx = start + i;
        if (idx < N_NODES) {
            rowptr[idx] = excl;
            cursor[idx] = excl;
            excl += cnt[idx];
        }
    }
    if (tid == 0) rowptr[N_NODES] = sums[1023];
}

__global__ void k_fill(const int* __restrict__ ei, int* __restrict__ cursor,
                       int* __restrict__ csr) {
    int e = blockIdx.x * blockDim.x + threadIdx.x;
    if (e < N_EDGES) {
        int src = ei[e];
        int dst = ei[N_EDGES + e];
        int pos = atomicAdd(&cursor[dst], 1);
        csr[pos] = src;
    }
}

// ---------- gather aggregation: agg[i,:] = sum_{j->i} h[j,:] ----------
__global__ void k_agg(const float* __restrict__ h, const int* __restrict__ rowptr,
                      const int* __restrict__ csr, float* __restrict__ agg) {
    int tid = blockIdx.x * blockDim.x + threadIdx.x;
    if (tid >= N_NODES * F4) return;
    int node = tid / F4;
    int fc = tid % F4;
    int beg = rowptr[node], end = rowptr[node + 1];
    const float4* h4 = (const float4*)h;
    float4 s = make_float4(0.f, 0.f, 0.f, 0.f);
    for (int e = beg; e < end; e++) {
        int src = csr[e];
        float4 v = h4[src * F4 + fc];
        s.x += v.x; s.y += v.y; s.z += v.z; s.w += v.w;
    }
    ((float4*)agg)[node * F4 + fc] = s;
}

// ---------- fused dual GEMM: out = agg@Wn + x@Ws + b (+relu) ----------
__device__ inline float4 f4fma(float s, float4 w, float4 a) {
    a.x += s * w.x; a.y += s * w.y; a.z += s * w.z; a.w += s * w.w;
    return a;
}

__global__ __launch_bounds__(GB) void k_gemm(
    const float* __restrict__ agg, const float* __restrict__ x,
    const float* __restrict__ Wn, const float* __restrict__ Ws,
    const float* __restrict__ b, float* __restrict__ out, int relu) {
    __shared__ float4 as4[TROWS * LDST];
    __shared__ float4 xs4[TROWS * LDST];
    int t = threadIdx.x;
    int row0 = blockIdx.x * TROWS;

    const float4* a4g = (const float4*)agg;
    const float4* x4g = (const float4*)x;
    for (int idx = t; idx < TROWS * F4; idx += GB) {
        int r = idx / F4, fc = idx % F4;
        int grow = row0 + r;
        float4 av = make_float4(0.f, 0.f, 0.f, 0.f);
        float4 xv = make_float4(0.f, 0.f, 0.f, 0.f);
        if (grow < N_NODES) {
            av = a4g[grow * F4 + fc];
            xv = x4g[grow * F4 + fc];
        }
        as4[r * LDST + fc] = av;
        xs4[r * LDST + fc] = xv;
    }
    __syncthreads();

    int jc = t % F4;  // float4 col group 0..23
    int rg = t / F4;  // row group 0..7
    const float4* Wn4 = (const float4*)Wn;
    const float4* Ws4 = (const float4*)Ws;
    float4 acc[8];
#pragma unroll
    for (int i = 0; i < 8; i++) acc[i] = make_float4(0.f, 0.f, 0.f, 0.f);

    for (int k0 = 0; k0 < F; k0 += 4) {
        float4 wn0 = Wn4[(k0 + 0) * F4 + jc];
        float4 wn1 = Wn4[(k0 + 1) * F4 + jc];
        float4 wn2 = Wn4[(k0 + 2) * F4 + jc];
        float4 wn3 = Wn4[(k0 + 3) * F4 + jc];
        float4 ws0 = Ws4[(k0 + 0) * F4 + jc];
        float4 ws1 = Ws4[(k0 + 1) * F4 + jc];
        float4 ws2 = Ws4[(k0 + 2) * F4 + jc];
        float4 ws3 = Ws4[(k0 + 3) * F4 + jc];
        int kq = k0 >> 2;
#pragma unroll
        for (int rr = 0; rr < 8; rr++) {
            int r = rg + rr * 8;
            float4 a4 = as4[r * LDST + kq];
            float4 x4 = xs4[r * LDST + kq];
            acc[rr] = f4fma(a4.x, wn0, acc[rr]);
            acc[rr] = f4fma(a4.y, wn1, acc[rr]);
            acc[rr] = f4fma(a4.z, wn2, acc[rr]);
            acc[rr] = f4fma(a4.w, wn3, acc[rr]);
            acc[rr] = f4fma(x4.x, ws0, acc[rr]);
            acc[rr] = f4fma(x4.y, ws1, acc[rr]);
            acc[rr] = f4fma(x4.z, ws2, acc[rr]);
            acc[rr] = f4fma(x4.w, ws3, acc[rr]);
        }
    }

    float4 bv = ((const float4*)b)[jc];
#pragma unroll
    for (int rr = 0; rr < 8; rr++) {
        int r = row0 + rg + rr * 8;
        if (r < N_NODES) {
            float4 v = acc[rr];
            v.x += bv.x; v.y += bv.y; v.z += bv.z; v.w += bv.w;
            if (relu) {
                v.x = fmaxf(v.x, 0.f); v.y = fmaxf(v.y, 0.f);
                v.z = fmaxf(v.z, 0.f); v.w = fmaxf(v.w, 0.f);
            }
            ((float4*)out)[r * F4 + jc] = v;
        }
    }
}

// ---------- pooling ----------
__global__ void k_bounds(const int* __restrict__ batch, int* __restrict__ gstart) {
    int i = blockIdx.x * blockDim.x + threadIdx.x;
    if (i >= N_NODES) return;
    int b = batch[i];
    int prev = (i == 0) ? -1 : batch[i - 1];
    for (int g = prev + 1; g <= b; g++) gstart[g] = i;
    if (i == N_NODES - 1) {
        for (int g = b + 1; g <= NG; g++) gstart[g] = N_NODES;
    }
}

__global__ void k_pool(const float* __restrict__ h, const int* __restrict__ gstart,
                       float* __restrict__ pooled) {
    int g = blockIdx.x;
    int f = threadIdx.x;
    if (f >= F) return;
    int beg = gstart[g], end = gstart[g + 1];
    float s = 0.f;
    for (int i = beg; i < end; i++) s += h[i * F + f];
    float c = (float)(end - beg);
    pooled[g * F + f] = s / fmaxf(c, 1.f);
}

__global__ void k_final(const float* __restrict__ pooled, const float* __restrict__ Wl,
                        const float* __restrict__ bl, float* __restrict__ out) {
    int t = blockIdx.x * blockDim.x + threadIdx.x;
    if (t >= NG * NC) return;
    int g = t / NC, c = t % NC;
    float s = bl[c];
    for (int k = 0; k < F; k++) s += pooled[g * F + k] * Wl[k * NC + c];
    out[t] = s;
}

extern "C" void kernel_launch(void* const* d_in, const int* in_sizes, int n_in,
                              void* d_out, int out_size, void* d_ws, size_t ws_size,
                              hipStream_t stream) {
    const float* x   = (const float*)d_in[0];
    const int* ei    = (const int*)d_in[1];
    // d_in[2] = edge_attr (unused)
    const int* batch = (const int*)d_in[3];
    const float* Wn1 = (const float*)d_in[4];
    const float* Ws1 = (const float*)d_in[5];
    const float* b1  = (const float*)d_in[6];
    const float* Wn2 = (const float*)d_in[7];
    const float* Ws2 = (const float*)d_in[8];
    const float* b2  = (const float*)d_in[9];
    const float* Wn3 = (const float*)d_in[10];
    const float* Ws3 = (const float*)d_in[11];
    const float* b3  = (const float*)d_in[12];
    const float* Wl  = (const float*)d_in[13];
    const float* bl  = (const float*)d_in[14];
    float* out = (float*)d_out;

    char* w = (char*)d_ws;
    float* hA     = (float*)w; w += (size_t)N_NODES * F * 4;
    float* hB     = (float*)w; w += (size_t)N_NODES * F * 4;
    float* agg    = (float*)w; w += (size_t)N_NODES * F * 4;
    float* pooled = (float*)w; w += (size_t)NG * F * 4;
    int* cnt      = (int*)w;   w += (size_t)N_NODES * 4;
    int* cursor   = (int*)w;   w += (size_t)N_NODES * 4;
    int* csr      = (int*)w;   w += (size_t)N_EDGES * 4;
    int* gstart   = (int*)w;   w += (size_t)(NG + 1) * 4;
    int* rowptr   = (int*)w;   w += (size_t)(N_NODES + 1) * 4;

    // CSR build
    hipMemsetAsync(cnt, 0, (size_t)N_NODES * 4, stream);
    k_count<<<(N_EDGES + 255) / 256, 256, 0, stream>>>(ei, cnt);
    k_scan<<<1, 1024, 0, stream>>>(cnt, rowptr, cursor);
    k_fill<<<(N_EDGES + 255) / 256, 256, 0, stream>>>(ei, cursor, csr);
    k_bounds<<<(N_NODES + 255) / 256, 256, 0, stream>>>(batch, gstart);

    int aggGrid = (N_NODES * F4 + 255) / 256;
    int gemmGrid = (N_NODES + TROWS - 1) / TROWS;

    // layer 1: in = x -> hA (relu)
    k_agg<<<aggGrid, 256, 0, stream>>>(x, rowptr, csr, agg);
    k_gemm<<<gemmGrid, GB, 0, stream>>>(agg, x, Wn1, Ws1, b1, hA, 1);
    // layer 2: hA -> hB (relu)
    k_agg<<<aggGrid, 256, 0, stream>>>(hA, rowptr, csr, agg);
    k_gemm<<<gemmGrid, GB, 0, stream>>>(agg, hA, Wn2, Ws2, b2, hB, 1);
    // layer 3: hB -> hA (no relu)
    k_agg<<<aggGrid, 256, 0, stream>>>(hB, rowptr, csr, agg);
    k_gemm<<<gemmGrid, GB, 0, stream>>>(agg, hB, Wn3, Ws3, b3, hA, 0);

    // pooling + head
    k_pool<<<NG, 128, 0, stream>>>(hA, gstart, pooled);
    k_final<<<(NG * NC + 255) / 256, 256, 0, stream>>>(pooled, Wl, bl, out);
}

// Round 2
// 600.240 us; speedup vs baseline: 1.1883x; 1.1883x over previous
//
#include <hip/hip_runtime.h>

#define N_NODES 50000
#define N_EDGES 800000
#define F 96
#define F4 24          // F/4
#define NG 100
#define NC 8
#define TROWS 64       // gemm row tile
#define GB 192         // gemm block threads: 8 row-groups x 24 float4-cols
#define LDST 25        // LDS row stride in float4 (=100 floats, pad kills bank conflicts)

// ---------- CSR build ----------
__global__ void k_count(const int* __restrict__ ei, int* __restrict__ cnt) {
    int e = blockIdx.x * blockDim.x + threadIdx.x;
    if (e < N_EDGES) atomicAdd(&cnt[ei[N_EDGES + e]], 1);  // dst row
}

__global__ __launch_bounds__(1024) void k_scan(const int* __restrict__ cnt,
                                               int* __restrict__ rowptr,
                                               int* __restrict__ cursor) {
    __shared__ int sums[1024];
    int tid = threadIdx.x;
    const int CH = (N_NODES + 1023) / 1024;  // 49
    int start = tid * CH;
    int s = 0;
    for (int i = 0; i < CH; i++) {
        int idx = start + i;
        if (idx < N_NODES) s += cnt[idx];
    }
    sums[tid] = s;
    __syncthreads();
    for (int off = 1; off < 1024; off <<= 1) {
        int v = 0;
        if (tid >= off) v = sums[tid - off];
        __syncthreads();
        if (tid >= off) sums[tid] += v;
        __syncthreads();
    }
    int excl = (tid == 0) ? 0 : sums[tid - 1];
    for (int i = 0; i < CH; i++) {
        int idx = start + i;
        if (idx < N_NODES) {
            rowptr[idx] = excl;
            cursor[idx] = excl;
            excl += cnt[idx];
        }
    }
    if (tid == 0) rowptr[N_NODES] = sums[1023];
}

__global__ void k_fill(const int* __restrict__ ei, int* __restrict__ cursor,
                       int* __restrict__ csr) {
    int e = blockIdx.x * blockDim.x + threadIdx.x;
    if (e < N_EDGES) {
        int src = ei[e];
        int dst = ei[N_EDGES + e];
        int pos = atomicAdd(&cursor[dst], 1);
        csr[pos] = src;
    }
}

// ---------- gather aggregation: agg[i,:] = sum_{j->i} h[j,:] ----------
__global__ void k_agg(const float* __restrict__ h, const int* __restrict__ rowptr,
                      const int* __restrict__ csr, float* __restrict__ agg) {
    int tid = blockIdx.x * blockDim.x + threadIdx.x;
    if (tid >= N_NODES * F4) return;
    int node = tid / F4;
    int fc = tid % F4;
    int beg = rowptr[node], end = rowptr[node + 1];
    const float4* h4 = (const float4*)h;
    float4 s = make_float4(0.f, 0.f, 0.f, 0.f);
    for (int e = beg; e < end; e++) {
        int src = csr[e];
        float4 v = h4[src * F4 + fc];
        s.x += v.x; s.y += v.y; s.z += v.z; s.w += v.w;
    }
    ((float4*)agg)[node * F4 + fc] = s;
}

// ---------- fused dual GEMM: out = agg@Wn + x@Ws + b (+relu) ----------
__device__ inline float4 f4fma(float s, float4 w, float4 a) {
    a.x += s * w.x; a.y += s * w.y; a.z += s * w.z; a.w += s * w.w;
    return a;
}

__global__ __launch_bounds__(GB) void k_gemm(
    const float* __restrict__ agg, const float* __restrict__ x,
    const float* __restrict__ Wn, const float* __restrict__ Ws,
    const float* __restrict__ b, float* __restrict__ out, int relu) {
    __shared__ float4 as4[TROWS * LDST];
    __shared__ float4 xs4[TROWS * LDST];
    int t = threadIdx.x;
    int row0 = blockIdx.x * TROWS;

    const float4* a4g = (const float4*)agg;
    const float4* x4g = (const float4*)x;
    for (int idx = t; idx < TROWS * F4; idx += GB) {
        int r = idx / F4, fc = idx % F4;
        int grow = row0 + r;
        float4 av = make_float4(0.f, 0.f, 0.f, 0.f);
        float4 xv = make_float4(0.f, 0.f, 0.f, 0.f);
        if (grow < N_NODES) {
            av = a4g[grow * F4 + fc];
            xv = x4g[grow * F4 + fc];
        }
        as4[r * LDST + fc] = av;
        xs4[r * LDST + fc] = xv;
    }
    __syncthreads();

    int jc = t % F4;  // float4 col group 0..23
    int rg = t / F4;  // row group 0..7
    const float4* Wn4 = (const float4*)Wn;
    const float4* Ws4 = (const float4*)Ws;
    float4 acc[8];
#pragma unroll
    for (int i = 0; i < 8; i++) acc[i] = make_float4(0.f, 0.f, 0.f, 0.f);

    for (int k0 = 0; k0 < F; k0 += 4) {
        float4 wn0 = Wn4[(k0 + 0) * F4 + jc];
        float4 wn1 = Wn4[(k0 + 1) * F4 + jc];
        float4 wn2 = Wn4[(k0 + 2) * F4 + jc];
        float4 wn3 = Wn4[(k0 + 3) * F4 + jc];
        float4 ws0 = Ws4[(k0 + 0) * F4 + jc];
        float4 ws1 = Ws4[(k0 + 1) * F4 + jc];
        float4 ws2 = Ws4[(k0 + 2) * F4 + jc];
        float4 ws3 = Ws4[(k0 + 3) * F4 + jc];
        int kq = k0 >> 2;
#pragma unroll
        for (int rr = 0; rr < 8; rr++) {
            int r = rg + rr * 8;
            float4 a4 = as4[r * LDST + kq];
            float4 x4 = xs4[r * LDST + kq];
            acc[rr] = f4fma(a4.x, wn0, acc[rr]);
            acc[rr] = f4fma(a4.y, wn1, acc[rr]);
            acc[rr] = f4fma(a4.z, wn2, acc[rr]);
            acc[rr] = f4fma(a4.w, wn3, acc[rr]);
            acc[rr] = f4fma(x4.x, ws0, acc[rr]);
            acc[rr] = f4fma(x4.y, ws1, acc[rr]);
            acc[rr] = f4fma(x4.z, ws2, acc[rr]);
            acc[rr] = f4fma(x4.w, ws3, acc[rr]);
        }
    }

    float4 bv = ((const float4*)b)[jc];
#pragma unroll
    for (int rr = 0; rr < 8; rr++) {
        int r = row0 + rg + rr * 8;
        if (r < N_NODES) {
            float4 v = acc[rr];
            v.x += bv.x; v.y += bv.y; v.z += bv.z; v.w += bv.w;
            if (relu) {
                v.x = fmaxf(v.x, 0.f); v.y = fmaxf(v.y, 0.f);
                v.z = fmaxf(v.z, 0.f); v.w = fmaxf(v.w, 0.f);
            }
            ((float4*)out)[r * F4 + jc] = v;
        }
    }
}

// ---------- pooling boundaries ----------
__global__ void k_bounds(const int* __restrict__ batch, int* __restrict__ gstart) {
    int i = blockIdx.x * blockDim.x + threadIdx.x;
    if (i >= N_NODES) return;
    int b = batch[i];
    int prev = (i == 0) ? -1 : batch[i - 1];
    for (int g = prev + 1; g <= b; g++) gstart[g] = i;
    if (i == N_NODES - 1) {
        for (int g = b + 1; g <= NG; g++) gstart[g] = N_NODES;
    }
}

// ---------- fused pool + head: out[g,:] = (mean_g h) @ Wl + bl ----------
// one block per graph; 24 float4-cols x 10 row-groups; rows contiguous (batch sorted)
__global__ __launch_bounds__(256) void k_pool(const float* __restrict__ h,
                                              const int* __restrict__ gstart,
                                              const float* __restrict__ Wl,
                                              const float* __restrict__ bl,
                                              float* __restrict__ out) {
    __shared__ float4 red[10][F4 + 1];
    __shared__ float pool[F];
    int g = blockIdx.x;
    int t = threadIdx.x;
    int fc = t % F4;
    int rg = t / F4;  // 0..10 (rg==10 for t>=240: idle in accumulation)
    int beg = gstart[g], end = gstart[g + 1];
    const float4* h4 = (const float4*)h;
    if (rg < 10) {
        float4 s = make_float4(0.f, 0.f, 0.f, 0.f);
        for (int r = beg + rg; r < end; r += 10) {
            float4 v = h4[r * F4 + fc];
            s.x += v.x; s.y += v.y; s.z += v.z; s.w += v.w;
        }
        red[rg][fc] = s;
    }
    __syncthreads();
    if (t < F4) {
        float4 a = red[0][t];
#pragma unroll
        for (int i = 1; i < 10; i++) {
            float4 v = red[i][t];
            a.x += v.x; a.y += v.y; a.z += v.z; a.w += v.w;
        }
        float inv = 1.f / fmaxf((float)(end - beg), 1.f);
        pool[t * 4 + 0] = a.x * inv;
        pool[t * 4 + 1] = a.y * inv;
        pool[t * 4 + 2] = a.z * inv;
        pool[t * 4 + 3] = a.w * inv;
    }
    __syncthreads();
    if (t < NC) {
        float s = bl[t];
#pragma unroll 8
        for (int k = 0; k < F; k++) s += pool[k] * Wl[k * NC + t];
        out[g * NC + t] = s;
    }
}

extern "C" void kernel_launch(void* const* d_in, const int* in_sizes, int n_in,
                              void* d_out, int out_size, void* d_ws, size_t ws_size,
                              hipStream_t stream) {
    const float* x   = (const float*)d_in[0];
    const int* ei    = (const int*)d_in[1];
    // d_in[2] = edge_attr (unused)
    const int* batch = (const int*)d_in[3];
    const float* Wn1 = (const float*)d_in[4];
    const float* Ws1 = (const float*)d_in[5];
    const float* b1  = (const float*)d_in[6];
    const float* Wn2 = (const float*)d_in[7];
    const float* Ws2 = (const float*)d_in[8];
    const float* b2  = (const float*)d_in[9];
    const float* Wn3 = (const float*)d_in[10];
    const float* Ws3 = (const float*)d_in[11];
    const float* b3  = (const float*)d_in[12];
    const float* Wl  = (const float*)d_in[13];
    const float* bl  = (const float*)d_in[14];
    float* out = (float*)d_out;

    char* w = (char*)d_ws;
    float* hA     = (float*)w; w += (size_t)N_NODES * F * 4;
    float* hB     = (float*)w; w += (size_t)N_NODES * F * 4;
    float* agg    = (float*)w; w += (size_t)N_NODES * F * 4;
    int* cnt      = (int*)w;   w += (size_t)N_NODES * 4;
    int* cursor   = (int*)w;   w += (size_t)N_NODES * 4;
    int* csr      = (int*)w;   w += (size_t)N_EDGES * 4;
    int* gstart   = (int*)w;   w += (size_t)(NG + 1) * 4;
    int* rowptr   = (int*)w;   w += (size_t)(N_NODES + 1) * 4;

    // CSR build
    hipMemsetAsync(cnt, 0, (size_t)N_NODES * 4, stream);
    k_count<<<(N_EDGES + 255) / 256, 256, 0, stream>>>(ei, cnt);
    k_scan<<<1, 1024, 0, stream>>>(cnt, rowptr, cursor);
    k_fill<<<(N_EDGES + 255) / 256, 256, 0, stream>>>(ei, cursor, csr);
    k_bounds<<<(N_NODES + 255) / 256, 256, 0, stream>>>(batch, gstart);

    int aggGrid = (N_NODES * F4 + 255) / 256;
    int gemmGrid = (N_NODES + TROWS - 1) / TROWS;

    // layer 1: in = x -> hA (relu)
    k_agg<<<aggGrid, 256, 0, stream>>>(x, rowptr, csr, agg);
    k_gemm<<<gemmGrid, GB, 0, stream>>>(agg, x, Wn1, Ws1, b1, hA, 1);
    // layer 2: hA -> hB (relu)
    k_agg<<<aggGrid, 256, 0, stream>>>(hA, rowptr, csr, agg);
    k_gemm<<<gemmGrid, GB, 0, stream>>>(agg, hA, Wn2, Ws2, b2, hB, 1);
    // layer 3: hB -> hA (no relu)
    k_agg<<<aggGrid, 256, 0, stream>>>(hB, rowptr, csr, agg);
    k_gemm<<<gemmGrid, GB, 0, stream>>>(agg, hB, Wn3, Ws3, b3, hA, 0);

    // fused pool + head
    k_pool<<<NG, 256, 0, stream>>>(hA, gstart, Wl, bl, out);
}

// Round 3
// 477.715 us; speedup vs baseline: 1.4931x; 1.2565x over previous
//
#include <hip/hip_runtime.h>

#define N_NODES 50000
#define N_EDGES 800000
#define F 96
#define F4 24          // F/4
#define NG 100
#define NC 8
#define TROWS 64       // gemm row tile
#define GB 192         // gemm block threads: 8 row-groups x 24 float4-cols
#define LDST 25        // LDS row stride in float4 (=100 floats, pad kills bank conflicts)
#define NB 196         // scan blocks: 196*256 = 50176 >= N_NODES

// ---------- CSR build ----------
__global__ void k_count(const int* __restrict__ ei, int* __restrict__ cnt) {
    int e = blockIdx.x * blockDim.x + threadIdx.x;
    if (e < N_EDGES) atomicAdd(&cnt[ei[N_EDGES + e]], 1);  // dst row
}

// hierarchical scan, stage A: per-block inclusive scan + block sums
__global__ __launch_bounds__(256) void k_scanA(const int* __restrict__ cnt,
                                               int* __restrict__ incl,
                                               int* __restrict__ bsum) {
    __shared__ int sh[256];
    int b = blockIdx.x, t = threadIdx.x;
    int i = b * 256 + t;
    int v = (i < N_NODES) ? cnt[i] : 0;
    sh[t] = v;
    __syncthreads();
    for (int off = 1; off < 256; off <<= 1) {
        int u = (t >= off) ? sh[t - off] : 0;
        __syncthreads();
        sh[t] += u;
        __syncthreads();
    }
    incl[i] = sh[t];
    if (t == 255) bsum[b] = sh[255];
}

// stage B: scan the 196 block sums (one small block)
__global__ __launch_bounds__(256) void k_scanB(const int* __restrict__ bsum,
                                               int* __restrict__ boff,
                                               int* __restrict__ rowptr) {
    __shared__ int sh[256];
    int t = threadIdx.x;
    int v = (t < NB) ? bsum[t] : 0;
    sh[t] = v;
    __syncthreads();
    for (int off = 1; off < 256; off <<= 1) {
        int u = (t >= off) ? sh[t - off] : 0;
        __syncthreads();
        sh[t] += u;
        __syncthreads();
    }
    if (t < NB) boff[t] = sh[t] - v;           // exclusive
    if (t == NB - 1) rowptr[N_NODES] = sh[t];  // total
}

// stage C: rowptr[i] = boff[b] + incl[i] - cnt[i]; cursor = rowptr
__global__ __launch_bounds__(256) void k_scanC(const int* __restrict__ cnt,
                                               const int* __restrict__ incl,
                                               const int* __restrict__ boff,
                                               int* __restrict__ rowptr,
                                               int* __restrict__ cursor) {
    int b = blockIdx.x, t = threadIdx.x;
    int i = b * 256 + t;
    if (i < N_NODES) {
        int r = boff[b] + incl[i] - cnt[i];
        rowptr[i] = r;
        cursor[i] = r;
    }
}

__global__ void k_fill(const int* __restrict__ ei, int* __restrict__ cursor,
                       int* __restrict__ csr) {
    int e = blockIdx.x * blockDim.x + threadIdx.x;
    if (e < N_EDGES) {
        int src = ei[e];
        int dst = ei[N_EDGES + e];
        int pos = atomicAdd(&cursor[dst], 1);
        csr[pos] = src;
    }
}

// ---------- gather aggregation: agg[i,:] = sum_{j->i} h[j,:] ----------
__global__ void k_agg(const float* __restrict__ h, const int* __restrict__ rowptr,
                      const int* __restrict__ csr, float* __restrict__ agg) {
    int tid = blockIdx.x * blockDim.x + threadIdx.x;
    if (tid >= N_NODES * F4) return;
    int node = tid / F4;
    int fc = tid % F4;
    int beg = rowptr[node], end = rowptr[node + 1];
    const float4* h4 = (const float4*)h;
    float4 s = make_float4(0.f, 0.f, 0.f, 0.f);
    for (int e = beg; e < end; e++) {
        int src = csr[e];
        float4 v = h4[src * F4 + fc];
        s.x += v.x; s.y += v.y; s.z += v.z; s.w += v.w;
    }
    ((float4*)agg)[node * F4 + fc] = s;
}

// ---------- fused dual GEMM: out = agg@Wn + x@Ws + b (+relu) ----------
__device__ inline float4 f4fma(float s, float4 w, float4 a) {
    a.x += s * w.x; a.y += s * w.y; a.z += s * w.z; a.w += s * w.w;
    return a;
}

__global__ __launch_bounds__(GB) void k_gemm(
    const float* __restrict__ agg, const float* __restrict__ x,
    const float* __restrict__ Wn, const float* __restrict__ Ws,
    const float* __restrict__ b, float* __restrict__ out, int relu) {
    __shared__ float4 as4[TROWS * LDST];
    __shared__ float4 xs4[TROWS * LDST];
    int t = threadIdx.x;
    int row0 = blockIdx.x * TROWS;

    const float4* a4g = (const float4*)agg;
    const float4* x4g = (const float4*)x;
    for (int idx = t; idx < TROWS * F4; idx += GB) {
        int r = idx / F4, fc = idx % F4;
        int grow = row0 + r;
        float4 av = make_float4(0.f, 0.f, 0.f, 0.f);
        float4 xv = make_float4(0.f, 0.f, 0.f, 0.f);
        if (grow < N_NODES) {
            av = a4g[grow * F4 + fc];
            xv = x4g[grow * F4 + fc];
        }
        as4[r * LDST + fc] = av;
        xs4[r * LDST + fc] = xv;
    }
    __syncthreads();

    int jc = t % F4;  // float4 col group 0..23
    int rg = t / F4;  // row group 0..7
    const float4* Wn4 = (const float4*)Wn;
    const float4* Ws4 = (const float4*)Ws;
    float4 acc[8];
#pragma unroll
    for (int i = 0; i < 8; i++) acc[i] = make_float4(0.f, 0.f, 0.f, 0.f);

    for (int k0 = 0; k0 < F; k0 += 4) {
        float4 wn0 = Wn4[(k0 + 0) * F4 + jc];
        float4 wn1 = Wn4[(k0 + 1) * F4 + jc];
        float4 wn2 = Wn4[(k0 + 2) * F4 + jc];
        float4 wn3 = Wn4[(k0 + 3) * F4 + jc];
        float4 ws0 = Ws4[(k0 + 0) * F4 + jc];
        float4 ws1 = Ws4[(k0 + 1) * F4 + jc];
        float4 ws2 = Ws4[(k0 + 2) * F4 + jc];
        float4 ws3 = Ws4[(k0 + 3) * F4 + jc];
        int kq = k0 >> 2;
#pragma unroll
        for (int rr = 0; rr < 8; rr++) {
            int r = rg + rr * 8;
            float4 a4 = as4[r * LDST + kq];
            float4 x4 = xs4[r * LDST + kq];
            acc[rr] = f4fma(a4.x, wn0, acc[rr]);
            acc[rr] = f4fma(a4.y, wn1, acc[rr]);
            acc[rr] = f4fma(a4.z, wn2, acc[rr]);
            acc[rr] = f4fma(a4.w, wn3, acc[rr]);
            acc[rr] = f4fma(x4.x, ws0, acc[rr]);
            acc[rr] = f4fma(x4.y, ws1, acc[rr]);
            acc[rr] = f4fma(x4.z, ws2, acc[rr]);
            acc[rr] = f4fma(x4.w, ws3, acc[rr]);
        }
    }

    float4 bv = ((const float4*)b)[jc];
#pragma unroll
    for (int rr = 0; rr < 8; rr++) {
        int r = row0 + rg + rr * 8;
        if (r < N_NODES) {
            float4 v = acc[rr];
            v.x += bv.x; v.y += bv.y; v.z += bv.z; v.w += bv.w;
            if (relu) {
                v.x = fmaxf(v.x, 0.f); v.y = fmaxf(v.y, 0.f);
                v.z = fmaxf(v.z, 0.f); v.w = fmaxf(v.w, 0.f);
            }
            ((float4*)out)[r * F4 + jc] = v;
        }
    }
}

// ---------- pooling boundaries ----------
__global__ void k_bounds(const int* __restrict__ batch, int* __restrict__ gstart) {
    int i = blockIdx.x * blockDim.x + threadIdx.x;
    if (i >= N_NODES) return;
    int b = batch[i];
    int prev = (i == 0) ? -1 : batch[i - 1];
    for (int g = prev + 1; g <= b; g++) gstart[g] = i;
    if (i == N_NODES - 1) {
        for (int g = b + 1; g <= NG; g++) gstart[g] = N_NODES;
    }
}

// ---------- fused pool + head: out[g,:] = (mean_g h) @ Wl + bl ----------
__global__ __launch_bounds__(256) void k_pool(const float* __restrict__ h,
                                              const int* __restrict__ gstart,
                                              const float* __restrict__ Wl,
                                              const float* __restrict__ bl,
                                              float* __restrict__ out) {
    __shared__ float4 red[10][F4 + 1];
    __shared__ float pool[F];
    int g = blockIdx.x;
    int t = threadIdx.x;
    int fc = t % F4;
    int rg = t / F4;  // 0..10 (rg==10 for t>=240: idle in accumulation)
    int beg = gstart[g], end = gstart[g + 1];
    const float4* h4 = (const float4*)h;
    if (rg < 10) {
        float4 s = make_float4(0.f, 0.f, 0.f, 0.f);
        for (int r = beg + rg; r < end; r += 10) {
            float4 v = h4[r * F4 + fc];
            s.x += v.x; s.y += v.y; s.z += v.z; s.w += v.w;
        }
        red[rg][fc] = s;
    }
    __syncthreads();
    if (t < F4) {
        float4 a = red[0][t];
#pragma unroll
        for (int i = 1; i < 10; i++) {
            float4 v = red[i][t];
            a.x += v.x; a.y += v.y; a.z += v.z; a.w += v.w;
        }
        float inv = 1.f / fmaxf((float)(end - beg), 1.f);
        pool[t * 4 + 0] = a.x * inv;
        pool[t * 4 + 1] = a.y * inv;
        pool[t * 4 + 2] = a.z * inv;
        pool[t * 4 + 3] = a.w * inv;
    }
    __syncthreads();
    if (t < NC) {
        float s = bl[t];
#pragma unroll 8
        for (int k = 0; k < F; k++) s += pool[k] * Wl[k * NC + t];
        out[g * NC + t] = s;
    }
}

extern "C" void kernel_launch(void* const* d_in, const int* in_sizes, int n_in,
                              void* d_out, int out_size, void* d_ws, size_t ws_size,
                              hipStream_t stream) {
    const float* x   = (const float*)d_in[0];
    const int* ei    = (const int*)d_in[1];
    // d_in[2] = edge_attr (unused)
    const int* batch = (const int*)d_in[3];
    const float* Wn1 = (const float*)d_in[4];
    const float* Ws1 = (const float*)d_in[5];
    const float* b1  = (const float*)d_in[6];
    const float* Wn2 = (const float*)d_in[7];
    const float* Ws2 = (const float*)d_in[8];
    const float* b2  = (const float*)d_in[9];
    const float* Wn3 = (const float*)d_in[10];
    const float* Ws3 = (const float*)d_in[11];
    const float* b3  = (const float*)d_in[12];
    const float* Wl  = (const float*)d_in[13];
    const float* bl  = (const float*)d_in[14];
    float* out = (float*)d_out;

    char* w = (char*)d_ws;
    float* hA     = (float*)w; w += (size_t)N_NODES * F * 4;
    float* hB     = (float*)w; w += (size_t)N_NODES * F * 4;
    float* agg    = (float*)w; w += (size_t)N_NODES * F * 4;
    int* cnt      = (int*)w;   w += (size_t)N_NODES * 4;
    int* cursor   = (int*)w;   w += (size_t)N_NODES * 4;
    int* csr      = (int*)w;   w += (size_t)N_EDGES * 4;
    int* gstart   = (int*)w;   w += (size_t)(NG + 1) * 4;
    int* rowptr   = (int*)w;   w += (size_t)(N_NODES + 1) * 4;
    int* incl     = (int*)w;   w += (size_t)(NB * 256) * 4;
    int* bsum     = (int*)w;   w += (size_t)NB * 4;
    int* boff     = (int*)w;   w += (size_t)NB * 4;

    // CSR build
    hipMemsetAsync(cnt, 0, (size_t)N_NODES * 4, stream);
    k_count<<<(N_EDGES + 255) / 256, 256, 0, stream>>>(ei, cnt);
    k_scanA<<<NB, 256, 0, stream>>>(cnt, incl, bsum);
    k_scanB<<<1, 256, 0, stream>>>(bsum, boff, rowptr);
    k_scanC<<<NB, 256, 0, stream>>>(cnt, incl, boff, rowptr, cursor);
    k_fill<<<(N_EDGES + 255) / 256, 256, 0, stream>>>(ei, cursor, csr);
    k_bounds<<<(N_NODES + 255) / 256, 256, 0, stream>>>(batch, gstart);

    int aggGrid = (N_NODES * F4 + 255) / 256;
    int gemmGrid = (N_NODES + TROWS - 1) / TROWS;

    // layer 1: in = x -> hA (relu)
    k_agg<<<aggGrid, 256, 0, stream>>>(x, rowptr, csr, agg);
    k_gemm<<<gemmGrid, GB, 0, stream>>>(agg, x, Wn1, Ws1, b1, hA, 1);
    // layer 2: hA -> hB (relu)
    k_agg<<<aggGrid, 256, 0, stream>>>(hA, rowptr, csr, agg);
    k_gemm<<<gemmGrid, GB, 0, stream>>>(agg, hA, Wn2, Ws2, b2, hB, 1);
    // layer 3: hB -> hA (no relu)
    k_agg<<<aggGrid, 256, 0, stream>>>(hB, rowptr, csr, agg);
    k_gemm<<<gemmGrid, GB, 0, stream>>>(agg, hB, Wn3, Ws3, b3, hA, 0);

    // fused pool + head
    k_pool<<<NG, 256, 0, stream>>>(hA, gstart, Wl, bl, out);
}

// Round 4
// 442.732 us; speedup vs baseline: 1.6110x; 1.0790x over previous
//
#include <hip/hip_runtime.h>

#define N_NODES 50000
#define N_EDGES 800000
#define F 96
#define F4 24
#define NG 100
#define NC 8
#define NB 196         // scan blocks: 196*256 >= N_NODES
#define MT 64          // nodes per layer-block
#define LSTRIDE 200    // LDS A-tile row stride in ushorts (400B: 2-way bank alias = free)

typedef __attribute__((ext_vector_type(8))) short bf16x8;
typedef __attribute__((ext_vector_type(4))) float f32x4;

__device__ inline unsigned short f2b(float f) {  // fp32 -> bf16 RNE
    unsigned int u = __float_as_uint(f);
    u += 0x7fffu + ((u >> 16) & 1u);
    return (unsigned short)(u >> 16);
}

// ---------- CSR build ----------
__global__ void k_count(const int* __restrict__ ei, int* __restrict__ cnt) {
    int e = blockIdx.x * blockDim.x + threadIdx.x;
    if (e < N_EDGES) atomicAdd(&cnt[ei[N_EDGES + e]], 1);
}

__global__ __launch_bounds__(256) void k_scanA(const int* __restrict__ cnt,
                                               int* __restrict__ incl,
                                               int* __restrict__ bsum) {
    __shared__ int sh[256];
    int b = blockIdx.x, t = threadIdx.x;
    int i = b * 256 + t;
    int v = (i < N_NODES) ? cnt[i] : 0;
    sh[t] = v;
    __syncthreads();
    for (int off = 1; off < 256; off <<= 1) {
        int u = (t >= off) ? sh[t - off] : 0;
        __syncthreads();
        sh[t] += u;
        __syncthreads();
    }
    incl[i] = sh[t];
    if (t == 255) bsum[b] = sh[255];
}

__global__ __launch_bounds__(256) void k_scanB(const int* __restrict__ bsum,
                                               int* __restrict__ boff,
                                               int* __restrict__ rowptr) {
    __shared__ int sh[256];
    int t = threadIdx.x;
    int v = (t < NB) ? bsum[t] : 0;
    sh[t] = v;
    __syncthreads();
    for (int off = 1; off < 256; off <<= 1) {
        int u = (t >= off) ? sh[t - off] : 0;
        __syncthreads();
        sh[t] += u;
        __syncthreads();
    }
    if (t < NB) boff[t] = sh[t] - v;
    if (t == NB - 1) rowptr[N_NODES] = sh[t];
}

__global__ __launch_bounds__(256) void k_scanC(const int* __restrict__ cnt,
                                               const int* __restrict__ incl,
                                               const int* __restrict__ boff,
                                               int* __restrict__ rowptr,
                                               int* __restrict__ cursor) {
    int b = blockIdx.x, t = threadIdx.x;
    int i = b * 256 + t;
    if (i < N_NODES) {
        int r = boff[b] + incl[i] - cnt[i];
        rowptr[i] = r;
        cursor[i] = r;
    }
}

__global__ void k_fill(const int* __restrict__ ei, int* __restrict__ cursor,
                       int* __restrict__ csr) {
    int e = blockIdx.x * blockDim.x + threadIdx.x;
    if (e < N_EDGES) {
        int src = ei[e];
        int dst = ei[N_EDGES + e];
        int pos = atomicAdd(&cursor[dst], 1);
        csr[pos] = src;
    }
}

// ---------- prep: x -> bf16, W packing: WbT[l][n][k] = (k<96?Wn:Ws)[k%96][n] ----------
__global__ void k_prep(const float* __restrict__ x,
                       const float* __restrict__ Wn1, const float* __restrict__ Ws1,
                       const float* __restrict__ Wn2, const float* __restrict__ Ws2,
                       const float* __restrict__ Wn3, const float* __restrict__ Ws3,
                       unsigned short* __restrict__ xb, unsigned short* __restrict__ WbT) {
    int i = blockIdx.x * blockDim.x + threadIdx.x;
    if (i < N_NODES * F) xb[i] = f2b(x[i]);
    if (i < 3 * 192 * 96) {
        int l = i / (192 * 96), r = i % (192 * 96);
        int n = r / 192, k = r % 192;
        const float* Wn = (l == 0) ? Wn1 : (l == 1) ? Wn2 : Wn3;
        const float* Ws = (l == 0) ? Ws1 : (l == 1) ? Ws2 : Ws3;
        float v = (k < 96) ? Wn[k * 96 + n] : Ws[(k - 96) * 96 + n];
        WbT[i] = f2b(v);
    }
}

// ---------- fused layer: gather-agg (bf16) + MFMA dual-GEMM + bias/relu ----------
__global__ __launch_bounds__(256) void k_layer(
    const unsigned short* __restrict__ hin,  // [N][96] bf16
    const int* __restrict__ rowptr, const int* __restrict__ csr,
    const unsigned short* __restrict__ WbT,  // [96][192] bf16 (n-major)
    const float* __restrict__ bias,
    void* __restrict__ hout, int relu, int out_bf16) {
    __shared__ unsigned short A[MT * LSTRIDE];  // cols 0..95: agg, 96..191: self
    int t = threadIdx.x;
    int row0 = blockIdx.x * MT;

    if (t < 192) {
        // gather: 16 node-groups x 12 fc (16B = 8 bf16 per fc), 4 passes
        int fc = t % 12;
        int ng = t / 12;
        for (int c = 0; c < 4; c++) {
            int nl = c * 16 + ng;
            int node = row0 + nl;
            float acc[8] = {0.f, 0.f, 0.f, 0.f, 0.f, 0.f, 0.f, 0.f};
            if (node < N_NODES) {
                int beg = rowptr[node], end = rowptr[node + 1];
                for (int e = beg; e < end; e++) {
                    int src = csr[e];
                    uint4 u = *(const uint4*)(hin + (size_t)src * F + fc * 8);
                    unsigned int uu[4] = {u.x, u.y, u.z, u.w};
#pragma unroll
                    for (int q = 0; q < 4; q++) {
                        acc[2 * q]     += __uint_as_float(uu[q] << 16);
                        acc[2 * q + 1] += __uint_as_float(uu[q] & 0xffff0000u);
                    }
                }
            }
            uint4 p;
            p.x = ((unsigned int)f2b(acc[1]) << 16) | f2b(acc[0]);
            p.y = ((unsigned int)f2b(acc[3]) << 16) | f2b(acc[2]);
            p.z = ((unsigned int)f2b(acc[5]) << 16) | f2b(acc[4]);
            p.w = ((unsigned int)f2b(acc[7]) << 16) | f2b(acc[6]);
            *(uint4*)&A[nl * LSTRIDE + fc * 8] = p;
        }
    } else {
        // stage self rows into cols 96..191 (64 threads x 12 chunks, coalesced)
        int t2 = t - 192;
        for (int i = 0; i < 12; i++) {
            int idx = i * 64 + t2;        // 0..767
            int r = idx / 12, fc = idx % 12;
            int node = row0 + r;
            uint4 v = make_uint4(0u, 0u, 0u, 0u);
            if (node < N_NODES) v = *(const uint4*)(hin + (size_t)node * F + fc * 8);
            *(uint4*)&A[r * LSTRIDE + 96 + fc * 8] = v;
        }
    }
    __syncthreads();

    // MFMA: each wave does 16 rows x 96 cols, K=192
    int wave = t >> 6;
    int lane = t & 63;
    int m = lane & 15;
    int ko = (lane >> 4) * 8;

    float bv[6];
#pragma unroll
    for (int nt = 0; nt < 6; nt++) bv[nt] = bias[nt * 16 + m];

    f32x4 acc[6];
#pragma unroll
    for (int nt = 0; nt < 6; nt++) acc[nt] = (f32x4){0.f, 0.f, 0.f, 0.f};

#pragma unroll
    for (int ks = 0; ks < 6; ks++) {
        bf16x8 a = *(bf16x8*)&A[(wave * 16 + m) * LSTRIDE + ks * 32 + ko];
#pragma unroll
        for (int nt = 0; nt < 6; nt++) {
            bf16x8 b = *(const bf16x8*)(WbT + (size_t)(nt * 16 + m) * 192 + ks * 32 + ko);
            acc[nt] = __builtin_amdgcn_mfma_f32_16x16x32_bf16(a, b, acc[nt], 0, 0, 0);
        }
    }

#pragma unroll
    for (int nt = 0; nt < 6; nt++) {
        int col = nt * 16 + m;
#pragma unroll
        for (int r = 0; r < 4; r++) {
            int rl = wave * 16 + ((lane >> 4) << 2) + r;
            int node = row0 + rl;
            if (node < N_NODES) {
                float v = acc[nt][r] + bv[nt];
                if (relu) v = fmaxf(v, 0.f);
                if (out_bf16) ((unsigned short*)hout)[(size_t)node * F + col] = f2b(v);
                else ((float*)hout)[(size_t)node * F + col] = v;
            }
        }
    }
}

// ---------- pooling boundaries ----------
__global__ void k_bounds(const int* __restrict__ batch, int* __restrict__ gstart) {
    int i = blockIdx.x * blockDim.x + threadIdx.x;
    if (i >= N_NODES) return;
    int b = batch[i];
    int prev = (i == 0) ? -1 : batch[i - 1];
    for (int g = prev + 1; g <= b; g++) gstart[g] = i;
    if (i == N_NODES - 1) {
        for (int g = b + 1; g <= NG; g++) gstart[g] = N_NODES;
    }
}

// ---------- fused pool + head ----------
__global__ __launch_bounds__(256) void k_pool(const float* __restrict__ h,
                                              const int* __restrict__ gstart,
                                              const float* __restrict__ Wl,
                                              const float* __restrict__ bl,
                                              float* __restrict__ out) {
    __shared__ float4 red[10][F4 + 1];
    __shared__ float pool[F];
    int g = blockIdx.x;
    int t = threadIdx.x;
    int fc = t % F4;
    int rg = t / F4;
    int beg = gstart[g], end = gstart[g + 1];
    const float4* h4 = (const float4*)h;
    if (rg < 10) {
        float4 s = make_float4(0.f, 0.f, 0.f, 0.f);
        for (int r = beg + rg; r < end; r += 10) {
            float4 v = h4[r * F4 + fc];
            s.x += v.x; s.y += v.y; s.z += v.z; s.w += v.w;
        }
        red[rg][fc] = s;
    }
    __syncthreads();
    if (t < F4) {
        float4 a = red[0][t];
#pragma unroll
        for (int i = 1; i < 10; i++) {
            float4 v = red[i][t];
            a.x += v.x; a.y += v.y; a.z += v.z; a.w += v.w;
        }
        float inv = 1.f / fmaxf((float)(end - beg), 1.f);
        pool[t * 4 + 0] = a.x * inv;
        pool[t * 4 + 1] = a.y * inv;
        pool[t * 4 + 2] = a.z * inv;
        pool[t * 4 + 3] = a.w * inv;
    }
    __syncthreads();
    if (t < NC) {
        float s = bl[t];
#pragma unroll 8
        for (int k = 0; k < F; k++) s += pool[k] * Wl[k * NC + t];
        out[g * NC + t] = s;
    }
}

extern "C" void kernel_launch(void* const* d_in, const int* in_sizes, int n_in,
                              void* d_out, int out_size, void* d_ws, size_t ws_size,
                              hipStream_t stream) {
    const float* x   = (const float*)d_in[0];
    const int* ei    = (const int*)d_in[1];
    const int* batch = (const int*)d_in[3];
    const float* Wn1 = (const float*)d_in[4];
    const float* Ws1 = (const float*)d_in[5];
    const float* b1  = (const float*)d_in[6];
    const float* Wn2 = (const float*)d_in[7];
    const float* Ws2 = (const float*)d_in[8];
    const float* b2  = (const float*)d_in[9];
    const float* Wn3 = (const float*)d_in[10];
    const float* Ws3 = (const float*)d_in[11];
    const float* b3  = (const float*)d_in[12];
    const float* Wl  = (const float*)d_in[13];
    const float* bl  = (const float*)d_in[14];
    float* out = (float*)d_out;

    char* w = (char*)d_ws;
    float* h3f            = (float*)w;          w += (size_t)N_NODES * F * 4;   // fp32 layer-3 out
    unsigned short* xb    = (unsigned short*)w; w += (size_t)N_NODES * F * 2;
    unsigned short* h1b   = (unsigned short*)w; w += (size_t)N_NODES * F * 2;
    unsigned short* h2b   = (unsigned short*)w; w += (size_t)N_NODES * F * 2;
    unsigned short* WbT   = (unsigned short*)w; w += (size_t)3 * 192 * 96 * 2;
    w = (char*)(((size_t)w + 255) & ~(size_t)255);
    int* cnt    = (int*)w; w += (size_t)N_NODES * 4;
    int* cursor = (int*)w; w += (size_t)N_NODES * 4;
    int* csr    = (int*)w; w += (size_t)N_EDGES * 4;
    int* gstart = (int*)w; w += (size_t)(NG + 1) * 4;
    int* rowptr = (int*)w; w += (size_t)(N_NODES + 1) * 4;
    int* incl   = (int*)w; w += (size_t)(NB * 256) * 4;
    int* bsum   = (int*)w; w += (size_t)NB * 4;
    int* boff   = (int*)w; w += (size_t)NB * 4;

    // CSR build
    hipMemsetAsync(cnt, 0, (size_t)N_NODES * 4, stream);
    k_count<<<(N_EDGES + 255) / 256, 256, 0, stream>>>(ei, cnt);
    k_scanA<<<NB, 256, 0, stream>>>(cnt, incl, bsum);
    k_scanB<<<1, 256, 0, stream>>>(bsum, boff, rowptr);
    k_scanC<<<NB, 256, 0, stream>>>(cnt, incl, boff, rowptr, cursor);
    k_fill<<<(N_EDGES + 255) / 256, 256, 0, stream>>>(ei, cursor, csr);
    k_bounds<<<(N_NODES + 255) / 256, 256, 0, stream>>>(batch, gstart);
    k_prep<<<(N_NODES * F + 255) / 256, 256, 0, stream>>>(x, Wn1, Ws1, Wn2, Ws2, Wn3, Ws3, xb, WbT);

    int layerGrid = (N_NODES + MT - 1) / MT;
    k_layer<<<layerGrid, 256, 0, stream>>>(xb,  rowptr, csr, WbT,                 b1, h1b, 1, 1);
    k_layer<<<layerGrid, 256, 0, stream>>>(h1b, rowptr, csr, WbT + 192 * 96,      b2, h2b, 1, 1);
    k_layer<<<layerGrid, 256, 0, stream>>>(h2b, rowptr, csr, WbT + 2 * 192 * 96,  b3, h3f, 0, 0);

    k_pool<<<NG, 256, 0, stream>>>(h3f, gstart, Wl, bl, out);
}

// Round 5
// 340.330 us; speedup vs baseline: 2.0958x; 1.3009x over previous
//
#include <hip/hip_runtime.h>

#define N_NODES 50000
#define N_EDGES 800000
#define F 96
#define F4 24
#define NG 100
#define NC 8
#define NB 196         // scan blocks: 196*256 >= N_NODES
#define MT 32          // nodes per layer-block
#define LSTRIDE 200    // LDS A-tile row stride in ushorts (400B)

typedef __attribute__((ext_vector_type(8))) short bf16x8;
typedef __attribute__((ext_vector_type(4))) float f32x4;

__device__ inline unsigned short f2b(float f) {  // fp32 -> bf16 RNE
    unsigned int u = __float_as_uint(f);
    u += 0x7fffu + ((u >> 16) & 1u);
    return (unsigned short)(u >> 16);
}

__device__ inline void addu4(float* acc, uint4 u) {
    unsigned int uu[4] = {u.x, u.y, u.z, u.w};
#pragma unroll
    for (int q = 0; q < 4; q++) {
        acc[2 * q]     += __uint_as_float(uu[q] << 16);
        acc[2 * q + 1] += __uint_as_float(uu[q] & 0xffff0000u);
    }
}

// ---------- CSR build ----------
__global__ void k_count(const int* __restrict__ ei, int* __restrict__ cnt) {
    int e = blockIdx.x * blockDim.x + threadIdx.x;
    if (e < N_EDGES) atomicAdd(&cnt[ei[N_EDGES + e]], 1);
}

__global__ __launch_bounds__(256) void k_scanA(const int* __restrict__ cnt,
                                               int* __restrict__ incl,
                                               int* __restrict__ bsum) {
    __shared__ int sh[256];
    int b = blockIdx.x, t = threadIdx.x;
    int i = b * 256 + t;
    int v = (i < N_NODES) ? cnt[i] : 0;
    sh[t] = v;
    __syncthreads();
    for (int off = 1; off < 256; off <<= 1) {
        int u = (t >= off) ? sh[t - off] : 0;
        __syncthreads();
        sh[t] += u;
        __syncthreads();
    }
    incl[i] = sh[t];
    if (t == 255) bsum[b] = sh[255];
}

__global__ __launch_bounds__(256) void k_scanB(const int* __restrict__ bsum,
                                               int* __restrict__ boff,
                                               int* __restrict__ rowptr) {
    __shared__ int sh[256];
    int t = threadIdx.x;
    int v = (t < NB) ? bsum[t] : 0;
    sh[t] = v;
    __syncthreads();
    for (int off = 1; off < 256; off <<= 1) {
        int u = (t >= off) ? sh[t - off] : 0;
        __syncthreads();
        sh[t] += u;
        __syncthreads();
    }
    if (t < NB) boff[t] = sh[t] - v;
    if (t == NB - 1) rowptr[N_NODES] = sh[t];
}

__global__ __launch_bounds__(256) void k_scanC(const int* __restrict__ cnt,
                                               const int* __restrict__ incl,
                                               const int* __restrict__ boff,
                                               int* __restrict__ rowptr,
                                               int* __restrict__ cursor) {
    int b = blockIdx.x, t = threadIdx.x;
    int i = b * 256 + t;
    if (i < N_NODES) {
        int r = boff[b] + incl[i] - cnt[i];
        rowptr[i] = r;
        cursor[i] = r;
    }
}

__global__ void k_fill(const int* __restrict__ ei, int* __restrict__ cursor,
                       int* __restrict__ csr) {
    int e = blockIdx.x * blockDim.x + threadIdx.x;
    if (e < N_EDGES) {
        int src = ei[e];
        int dst = ei[N_EDGES + e];
        int pos = atomicAdd(&cursor[dst], 1);
        csr[pos] = src;
    }
}

// ---------- prep: x -> bf16, W packing: WbT[l][n][k] = (k<96?Wn:Ws)[k%96][n] ----------
__global__ void k_prep(const float* __restrict__ x,
                       const float* __restrict__ Wn1, const float* __restrict__ Ws1,
                       const float* __restrict__ Wn2, const float* __restrict__ Ws2,
                       const float* __restrict__ Wn3, const float* __restrict__ Ws3,
                       unsigned short* __restrict__ xb, unsigned short* __restrict__ WbT) {
    int i = blockIdx.x * blockDim.x + threadIdx.x;
    if (i < N_NODES * F) xb[i] = f2b(x[i]);
    if (i < 3 * 192 * 96) {
        int l = i / (192 * 96), r = i % (192 * 96);
        int n = r / 192, k = r % 192;
        const float* Wn = (l == 0) ? Wn1 : (l == 1) ? Wn2 : Wn3;
        const float* Ws = (l == 0) ? Ws1 : (l == 1) ? Ws2 : Ws3;
        float v = (k < 96) ? Wn[k * 96 + n] : Ws[(k - 96) * 96 + n];
        WbT[i] = f2b(v);
    }
}

// ---------- fused layer: gather-agg (bf16, 4x-unrolled MLP) + MFMA + bias/relu ----------
__global__ __launch_bounds__(128) void k_layer(
    const unsigned short* __restrict__ hin,  // [N][96] bf16
    const int* __restrict__ rowptr, const int* __restrict__ csr,
    const unsigned short* __restrict__ WbT,  // [96][192] bf16 (n-major)
    const float* __restrict__ bias,
    void* __restrict__ hout, int relu, int out_bf16) {
    __shared__ unsigned short A[MT * LSTRIDE];  // cols 0..95: agg, 96..191: self
    int t = threadIdx.x;
    int row0 = blockIdx.x * MT;

    // gather: 32 nodes x 12 fc-chunks(8 bf16 = 16B) = 384 items, 3 passes
#pragma unroll
    for (int p = 0; p < 3; p++) {
        int idx = p * 128 + t;
        int nl = idx / 12, fc = idx % 12;
        int node = row0 + nl;
        float acc[8] = {0.f, 0.f, 0.f, 0.f, 0.f, 0.f, 0.f, 0.f};
        if (node < N_NODES) {
            int beg = rowptr[node], end = rowptr[node + 1];
            int e = beg;
            for (; e + 4 <= end; e += 4) {
                int s0 = csr[e], s1 = csr[e + 1], s2 = csr[e + 2], s3 = csr[e + 3];
                uint4 u0 = *(const uint4*)(hin + (size_t)s0 * F + fc * 8);
                uint4 u1 = *(const uint4*)(hin + (size_t)s1 * F + fc * 8);
                uint4 u2 = *(const uint4*)(hin + (size_t)s2 * F + fc * 8);
                uint4 u3 = *(const uint4*)(hin + (size_t)s3 * F + fc * 8);
                addu4(acc, u0); addu4(acc, u1); addu4(acc, u2); addu4(acc, u3);
            }
            for (; e < end; e++) {
                int s0 = csr[e];
                uint4 u0 = *(const uint4*)(hin + (size_t)s0 * F + fc * 8);
                addu4(acc, u0);
            }
        }
        uint4 pk;
        pk.x = ((unsigned int)f2b(acc[1]) << 16) | f2b(acc[0]);
        pk.y = ((unsigned int)f2b(acc[3]) << 16) | f2b(acc[2]);
        pk.z = ((unsigned int)f2b(acc[5]) << 16) | f2b(acc[4]);
        pk.w = ((unsigned int)f2b(acc[7]) << 16) | f2b(acc[6]);
        *(uint4*)&A[nl * LSTRIDE + fc * 8] = pk;
    }

    // self rows into cols 96..191: 384 items, 3 passes
#pragma unroll
    for (int p = 0; p < 3; p++) {
        int idx = p * 128 + t;
        int nl = idx / 12, fc = idx % 12;
        int node = row0 + nl;
        uint4 v = make_uint4(0u, 0u, 0u, 0u);
        if (node < N_NODES) v = *(const uint4*)(hin + (size_t)node * F + fc * 8);
        *(uint4*)&A[nl * LSTRIDE + 96 + fc * 8] = v;
    }
    __syncthreads();

    // MFMA: 2 waves x (16 rows x 96 cols), K=192
    int wave = t >> 6;
    int lane = t & 63;
    int m = lane & 15;
    int ko = (lane >> 4) * 8;

    float bv[6];
#pragma unroll
    for (int nt = 0; nt < 6; nt++) bv[nt] = bias[nt * 16 + m];

    f32x4 acc[6];
#pragma unroll
    for (int nt = 0; nt < 6; nt++) acc[nt] = (f32x4){0.f, 0.f, 0.f, 0.f};

#pragma unroll
    for (int ks = 0; ks < 6; ks++) {
        bf16x8 a = *(bf16x8*)&A[(wave * 16 + m) * LSTRIDE + ks * 32 + ko];
#pragma unroll
        for (int nt = 0; nt < 6; nt++) {
            bf16x8 b = *(const bf16x8*)(WbT + (size_t)(nt * 16 + m) * 192 + ks * 32 + ko);
            acc[nt] = __builtin_amdgcn_mfma_f32_16x16x32_bf16(a, b, acc[nt], 0, 0, 0);
        }
    }

#pragma unroll
    for (int nt = 0; nt < 6; nt++) {
        int col = nt * 16 + m;
#pragma unroll
        for (int r = 0; r < 4; r++) {
            int rl = wave * 16 + ((lane >> 4) << 2) + r;
            int node = row0 + rl;
            if (node < N_NODES) {
                float v = acc[nt][r] + bv[nt];
                if (relu) v = fmaxf(v, 0.f);
                if (out_bf16) ((unsigned short*)hout)[(size_t)node * F + col] = f2b(v);
                else ((float*)hout)[(size_t)node * F + col] = v;
            }
        }
    }
}

// ---------- pooling boundaries ----------
__global__ void k_bounds(const int* __restrict__ batch, int* __restrict__ gstart) {
    int i = blockIdx.x * blockDim.x + threadIdx.x;
    if (i >= N_NODES) return;
    int b = batch[i];
    int prev = (i == 0) ? -1 : batch[i - 1];
    for (int g = prev + 1; g <= b; g++) gstart[g] = i;
    if (i == N_NODES - 1) {
        for (int g = b + 1; g <= NG; g++) gstart[g] = N_NODES;
    }
}

// ---------- fused pool + head ----------
__global__ __launch_bounds__(256) void k_pool(const float* __restrict__ h,
                                              const int* __restrict__ gstart,
                                              const float* __restrict__ Wl,
                                              const float* __restrict__ bl,
                                              float* __restrict__ out) {
    __shared__ float4 red[10][F4 + 1];
    __shared__ float pool[F];
    int g = blockIdx.x;
    int t = threadIdx.x;
    int fc = t % F4;
    int rg = t / F4;
    int beg = gstart[g], end = gstart[g + 1];
    const float4* h4 = (const float4*)h;
    if (rg < 10) {
        float4 s = make_float4(0.f, 0.f, 0.f, 0.f);
        for (int r = beg + rg; r < end; r += 10) {
            float4 v = h4[r * F4 + fc];
            s.x += v.x; s.y += v.y; s.z += v.z; s.w += v.w;
        }
        red[rg][fc] = s;
    }
    __syncthreads();
    if (t < F4) {
        float4 a = red[0][t];
#pragma unroll
        for (int i = 1; i < 10; i++) {
            float4 v = red[i][t];
            a.x += v.x; a.y += v.y; a.z += v.z; a.w += v.w;
        }
        float inv = 1.f / fmaxf((float)(end - beg), 1.f);
        pool[t * 4 + 0] = a.x * inv;
        pool[t * 4 + 1] = a.y * inv;
        pool[t * 4 + 2] = a.z * inv;
        pool[t * 4 + 3] = a.w * inv;
    }
    __syncthreads();
    if (t < NC) {
        float s = bl[t];
#pragma unroll 8
        for (int k = 0; k < F; k++) s += pool[k] * Wl[k * NC + t];
        out[g * NC + t] = s;
    }
}

extern "C" void kernel_launch(void* const* d_in, const int* in_sizes, int n_in,
                              void* d_out, int out_size, void* d_ws, size_t ws_size,
                              hipStream_t stream) {
    const float* x   = (const float*)d_in[0];
    const int* ei    = (const int*)d_in[1];
    const int* batch = (const int*)d_in[3];
    const float* Wn1 = (const float*)d_in[4];
    const float* Ws1 = (const float*)d_in[5];
    const float* b1  = (const float*)d_in[6];
    const float* Wn2 = (const float*)d_in[7];
    const float* Ws2 = (const float*)d_in[8];
    const float* b2  = (const float*)d_in[9];
    const float* Wn3 = (const float*)d_in[10];
    const float* Ws3 = (const float*)d_in[11];
    const float* b3  = (const float*)d_in[12];
    const float* Wl  = (const float*)d_in[13];
    const float* bl  = (const float*)d_in[14];
    float* out = (float*)d_out;

    char* w = (char*)d_ws;
    float* h3f            = (float*)w;          w += (size_t)N_NODES * F * 4;
    unsigned short* xb    = (unsigned short*)w; w += (size_t)N_NODES * F * 2;
    unsigned short* h1b   = (unsigned short*)w; w += (size_t)N_NODES * F * 2;
    unsigned short* h2b   = (unsigned short*)w; w += (size_t)N_NODES * F * 2;
    unsigned short* WbT   = (unsigned short*)w; w += (size_t)3 * 192 * 96 * 2;
    w = (char*)(((size_t)w + 255) & ~(size_t)255);
    int* cnt    = (int*)w; w += (size_t)N_NODES * 4;
    int* cursor = (int*)w; w += (size_t)N_NODES * 4;
    int* csr    = (int*)w; w += (size_t)N_EDGES * 4;
    int* gstart = (int*)w; w += (size_t)(NG + 1) * 4;
    int* rowptr = (int*)w; w += (size_t)(N_NODES + 1) * 4;
    int* incl   = (int*)w; w += (size_t)(NB * 256) * 4;
    int* bsum   = (int*)w; w += (size_t)NB * 4;
    int* boff   = (int*)w; w += (size_t)NB * 4;

    // CSR build
    hipMemsetAsync(cnt, 0, (size_t)N_NODES * 4, stream);
    k_count<<<(N_EDGES + 255) / 256, 256, 0, stream>>>(ei, cnt);
    k_scanA<<<NB, 256, 0, stream>>>(cnt, incl, bsum);
    k_scanB<<<1, 256, 0, stream>>>(bsum, boff, rowptr);
    k_scanC<<<NB, 256, 0, stream>>>(cnt, incl, boff, rowptr, cursor);
    k_fill<<<(N_EDGES + 255) / 256, 256, 0, stream>>>(ei, cursor, csr);
    k_bounds<<<(N_NODES + 255) / 256, 256, 0, stream>>>(batch, gstart);
    k_prep<<<(N_NODES * F + 255) / 256, 256, 0, stream>>>(x, Wn1, Ws1, Wn2, Ws2, Wn3, Ws3, xb, WbT);

    int layerGrid = (N_NODES + MT - 1) / MT;
    k_layer<<<layerGrid, 128, 0, stream>>>(xb,  rowptr, csr, WbT,                 b1, h1b, 1, 1);
    k_layer<<<layerGrid, 128, 0, stream>>>(h1b, rowptr, csr, WbT + 192 * 96,      b2, h2b, 1, 1);
    k_layer<<<layerGrid, 128, 0, stream>>>(h2b, rowptr, csr, WbT + 2 * 192 * 96,  b3, h3f, 0, 0);

    k_pool<<<NG, 256, 0, stream>>>(h3f, gstart, Wl, bl, out);
}